// Round 2
// baseline (937.083 us; speedup 1.0000x reference)
//
#include <hip/hip_runtime.h>

#define EPS 1e-5f
#define B 8
#define C 256
#define NPIX 4096      // 64*64
#define NCH 144        // rows: 0..63 q_bn, 64..127 v_bn, 128..143 kf(raw)
#define ROW_V 64
#define ROW_KF 128
#define PAD 11

// workspace layout (float offsets)
#define WP_OFF    0u          // Wt transposed: 256*144 = 36864
#define BIAS_OFF  36864u      // 144
#define PROJ_OFF  37120u      // 8*144*4096 = 4718592
#define RMAX_OFF  4755712u    // 128
#define RSC_OFF   4755840u    // 128
#define LC_OFF    4755968u    // 8*16*64 = 8192
#define ET_OFF    4764160u    // 529*16 = 8464  (end 4772624 floats = 19.1 MB)

// ---------------- 1) fold BN into transposed projection weights Wt[c][144] ----------
__global__ __launch_bounds__(256) void k_wfold(
    const float* __restrict__ Wq, const float* __restrict__ qg, const float* __restrict__ qb,
    const float* __restrict__ qm, const float* __restrict__ qv,
    const float* __restrict__ Wk, const float* __restrict__ Wv,
    const float* __restrict__ vg, const float* __restrict__ vb,
    const float* __restrict__ vm, const float* __restrict__ vvar,
    float* __restrict__ Wt, float* __restrict__ biasp) {
  int o = blockIdx.x;   // 0..143
  int t = threadIdx.x;  // 0..255 = c
  const float* src; float s, bias;
  if (o < 64) {
    s = qg[o] * rsqrtf(qv[o] + EPS); bias = qb[o] - qm[o] * s; src = Wq + o * C;
  } else if (o < 128) {
    int i = o - 64;
    s = vg[i] * rsqrtf(vvar[i] + EPS); bias = vb[i] - vm[i] * s; src = Wv + i * C;
  } else {
    int i = o - 128; s = 1.f; bias = 0.f; src = Wk + i * C;
  }
  Wt[t * NCH + o] = src[t] * s;   // transposed: c-major rows of 144
  if (t == 0) biasp[o] = bias;
}

// ---------------- 1b) transpose embedding: et[tap][k], 64B-aligned rows ----------
__global__ __launch_bounds__(256) void k_etrans(
    const float* __restrict__ emb, float* __restrict__ et) {
  int i = blockIdx.x * 256 + threadIdx.x;   // 0..8463
  if (i < 529 * 16) {
    int tap = i / 16, k = i % 16;
    et[i] = emb[k * 529 + tap];
  }
}

// ---------------- 2) projection GEMM: proj[b][o][n] = sum_c Wt[c][o] x[b][c][n] + b'[o] ----
__global__ __launch_bounds__(256) void k_proj(
    const float* __restrict__ x, const float* __restrict__ Wt,
    const float* __restrict__ biasp, float* __restrict__ proj) {
  int g = blockIdx.x;     // 0..2 (48 ch each)
  int tile = blockIdx.y;  // 0..15 (256 px each)
  int b = blockIdx.z;
  int t = threadIdx.x;
  int px = tile * 256 + t;
  const float* xb = x + (size_t)b * C * NPIX + px;
  float acc[48];
  #pragma unroll
  for (int i = 0; i < 48; i++) acc[i] = 0.f;
  #pragma unroll 2
  for (int c = 0; c < C; c++) {
    float xv = xb[(size_t)c * NPIX];
    const float* wrow = Wt + c * NCH + g * 48;   // uniform -> s_load
    #pragma unroll
    for (int i = 0; i < 48; i++) acc[i] += xv * wrow[i];
  }
  float* ob = proj + ((size_t)b * NCH + g * 48) * NPIX + px;
  #pragma unroll
  for (int i = 0; i < 48; i++) ob[(size_t)i * NPIX] = acc[i] + biasp[g * 48 + i];
}

// ---------------- 3) softmax row stats for kf rows ----------------
__global__ __launch_bounds__(256) void k_softstat(
    const float* __restrict__ proj, float* __restrict__ rmax, float* __restrict__ rsc) {
  int k = blockIdx.x, b = blockIdx.y, t = threadIdx.x;
  const float* row = proj + ((size_t)b * NCH + ROW_KF + k) * NPIX;
  __shared__ float sd[256];
  float m = -1e30f;
  for (int n = t; n < NPIX; n += 256) m = fmaxf(m, row[n]);
  sd[t] = m; __syncthreads();
  for (int s = 128; s > 0; s >>= 1) { if (t < s) sd[t] = fmaxf(sd[t], sd[t + s]); __syncthreads(); }
  m = sd[0]; __syncthreads();
  float sum = 0.f;
  for (int n = t; n < NPIX; n += 256) sum += __expf(row[n] - m);
  sd[t] = sum; __syncthreads();
  for (int s = 128; s > 0; s >>= 1) { if (t < s) sd[t] += sd[t + s]; __syncthreads(); }
  if (t == 0) { rmax[b * 16 + k] = m; rsc[b * 16 + k] = 1.f / sd[0]; }
}

// ---------------- 4) lambda_c partial: 8 n-chunks, atomicAdd into zeroed lc ----------
__global__ __launch_bounds__(256) void k_lambda_c(
    const float* __restrict__ proj, const float* __restrict__ rmax,
    const float* __restrict__ rsc, float* __restrict__ lc) {
  int k = blockIdx.x, chunk = blockIdx.y, b = blockIdx.z, t = threadIdx.x;
  const float* row = proj + ((size_t)b * NCH + ROW_KF + k) * NPIX;
  const float* vbase = proj + ((size_t)b * NCH + ROW_V) * NPIX;
  float m = rmax[b * 16 + k], sc = rsc[b * 16 + k];
  float acc[64];
  #pragma unroll
  for (int i = 0; i < 64; i++) acc[i] = 0.f;
  for (int it = 0; it < 2; ++it) {
    int n = chunk * 512 + it * 256 + t;
    float p = __expf(row[n] - m) * sc;
    #pragma unroll
    for (int vv = 0; vv < 64; vv++) acc[vv] += p * vbase[(size_t)vv * NPIX + n];
  }
  int lane = t & 63, wid = t >> 6;
  float keep = 0.f;
  #pragma unroll
  for (int vv = 0; vv < 64; vv++) {
    float s = acc[vv];
    #pragma unroll
    for (int off = 32; off > 0; off >>= 1) s += __shfl_xor(s, off);
    if (lane == vv) keep = s;
  }
  __shared__ float sh[4 * 64];
  sh[wid * 64 + lane] = keep;
  __syncthreads();
  if (t < 64) {
    float val = sh[t] + sh[64 + t] + sh[128 + t] + sh[192 + t];
    atomicAdd(&lc[((size_t)b * 16 + k) * 64 + t], val);
  }
}

// ---------------- 5) fused 23x23 conv + k-contraction with q + y_c -----------
// E comes from global via wave-uniform addresses -> scalar loads (SMEM pipe),
// leaving only 4 vh b32 reads per tap on the LDS pipe -> VALU-bound.
#define VH_PITCH 88
#define VH_ROWS 38
__global__ __launch_bounds__(256) void k_conv_fused(
    const float* __restrict__ proj, const float* __restrict__ et,
    const float* __restrict__ lc, float* __restrict__ out) {
  int v = blockIdx.x;     // 0..63 (fastest: blocks sharing (b,tile) reuse q tile in L2)
  int tile = blockIdx.y;  // 0..3
  int b = blockIdx.z;
  int t = threadIdx.x;
  __shared__ float vh[VH_ROWS * VH_PITCH];
  int r0 = tile * 16;
  const float* vrow = proj + ((size_t)b * NCH + ROW_V + v) * NPIX;
  for (int i = t; i < VH_ROWS * 86; i += 256) {
    int r = i / 86, cc = i % 86;
    int gr = r0 + r - PAD, gc = cc - PAD;
    float val = 0.f;
    if (gr >= 0 && gr < 64 && gc >= 0 && gc < 64) val = vrow[gr * 64 + gc];
    vh[r * VH_PITCH + cc] = val;
  }
  __syncthreads();
  int col = t & 63, rq = t >> 6;  // 4 rows rq*4..rq*4+3 at this col
  float lp[16][4];
  #pragma unroll
  for (int k = 0; k < 16; k++)
    #pragma unroll
    for (int i = 0; i < 4; i++) lp[k][i] = 0.f;
  for (int ky = 0; ky < 23; ky++) {
    const float* erow = et + (ky * 23) * 16;           // uniform
    const float* vbase = vh + (rq * 4 + ky) * VH_PITCH + col;
    #pragma unroll 1
    for (int kx = 0; kx < 23; kx++) {
      float vv0 = vbase[kx];
      float vv1 = vbase[VH_PITCH + kx];
      float vv2 = vbase[2 * VH_PITCH + kx];
      float vv3 = vbase[3 * VH_PITCH + kx];
      const float* ee = erow + kx * 16;                // uniform -> s_load_dwordx16
      #pragma unroll
      for (int k = 0; k < 16; k++) {
        float e = ee[k];
        lp[k][0] += vv0 * e;
        lp[k][1] += vv1 * e;
        lp[k][2] += vv2 * e;
        lp[k][3] += vv3 * e;
      }
    }
  }
  float lcv[16];
  #pragma unroll
  for (int k = 0; k < 16; k++) lcv[k] = lc[((size_t)b * 16 + k) * 64 + v];  // uniform
  const float* qb = proj + (size_t)b * NCH * NPIX;
  float* ob = out + (size_t)b * 256 * NPIX;
  #pragma unroll
  for (int i = 0; i < 4; i++) {
    int n = (r0 + rq * 4 + i) * 64 + col;
    float y0 = 0.f, y1 = 0.f, y2 = 0.f, y3 = 0.f;
    #pragma unroll
    for (int k = 0; k < 16; k++) {
      float mz = lp[k][i] + lcv[k];
      y0 += qb[(size_t)(0 * 16 + k) * NPIX + n] * mz;
      y1 += qb[(size_t)(1 * 16 + k) * NPIX + n] * mz;
      y2 += qb[(size_t)(2 * 16 + k) * NPIX + n] * mz;
      y3 += qb[(size_t)(3 * 16 + k) * NPIX + n] * mz;
    }
    ob[(size_t)(0 * 64 + v) * NPIX + n] = y0;
    ob[(size_t)(1 * 64 + v) * NPIX + n] = y1;
    ob[(size_t)(2 * 64 + v) * NPIX + n] = y2;
    ob[(size_t)(3 * 64 + v) * NPIX + n] = y3;
  }
}

extern "C" void kernel_launch(void* const* d_in, const int* in_sizes, int n_in,
                              void* d_out, int out_size, void* d_ws, size_t ws_size,
                              hipStream_t stream) {
  const float* x    = (const float*)d_in[0];
  const float* Wq   = (const float*)d_in[1];
  const float* qg   = (const float*)d_in[2];
  const float* qbta = (const float*)d_in[3];
  const float* qm   = (const float*)d_in[4];
  const float* qv   = (const float*)d_in[5];
  const float* Wk   = (const float*)d_in[6];
  const float* Wv   = (const float*)d_in[7];
  const float* vg   = (const float*)d_in[8];
  const float* vb   = (const float*)d_in[9];
  const float* vm   = (const float*)d_in[10];
  const float* vvar = (const float*)d_in[11];
  const float* emb  = (const float*)d_in[12];
  float* ws   = (float*)d_ws;
  float* Wt   = ws + WP_OFF;
  float* bp   = ws + BIAS_OFF;
  float* proj = ws + PROJ_OFF;
  float* rmax = ws + RMAX_OFF;
  float* rsc  = ws + RSC_OFF;
  float* lcw  = ws + LC_OFF;
  float* etw  = ws + ET_OFF;
  float* out  = (float*)d_out;

  hipLaunchKernelGGL(k_wfold, dim3(144), dim3(256), 0, stream,
                     Wq, qg, qbta, qm, qv, Wk, Wv, vg, vb, vm, vvar, Wt, bp);
  hipLaunchKernelGGL(k_etrans, dim3(34), dim3(256), 0, stream, emb, etw);
  hipMemsetAsync(lcw, 0, 16 * 64 * B * sizeof(float), stream);
  hipLaunchKernelGGL(k_proj, dim3(3, 16, 8), dim3(256), 0, stream, x, Wt, bp, proj);
  hipLaunchKernelGGL(k_softstat, dim3(16, 8), dim3(256), 0, stream, proj, rmax, rsc);
  hipLaunchKernelGGL(k_lambda_c, dim3(16, 8, 8), dim3(256), 0, stream, proj, rmax, rsc, lcw);
  hipLaunchKernelGGL(k_conv_fused, dim3(64, 4, 8), dim3(256), 0, stream, proj, etw, lcw, out);
}